// Round 2
// baseline (66.851 us; speedup 1.0000x reference)
//
#include <hip/hip_runtime.h>

// HybridQAE: 4-qubit encoder (RY data, CNOT chain, RY trainable; RZ phases
// cancel under |psi|^2) + 3-layer MLP. One thread = one sample.

__global__ __launch_bounds__(256) void hqae_kernel(
    const float* __restrict__ x,
    const float* __restrict__ qw,
    const float* __restrict__ W1, const float* __restrict__ b1,
    const float* __restrict__ W2, const float* __restrict__ b2,
    const float* __restrict__ W3, const float* __restrict__ b3,
    float* __restrict__ out)
{
    __shared__ float sW1[64];
    __shared__ float sb1[16];
    __shared__ float sW2[512];
    __shared__ float sb2[32];
    __shared__ float sW3[512];
    __shared__ float sb3[16];
    __shared__ float scw[4], ssw[4];

    const int tid = threadIdx.x;
    // ---- stage weights into LDS (broadcast-read later) ----
    for (int t = tid; t < 512; t += 256) { sW2[t] = W2[t]; sW3[t] = W3[t]; }
    if (tid < 64) sW1[tid] = W1[tid];
    if (tid < 16) { sb1[tid] = b1[tid]; sb3[tid] = b3[tid]; }
    if (tid < 32) sb2[tid] = b2[tid];
    if (tid < 4) {
        float a = qw[2 * tid] * 0.5f;   // RY half-angle; RZ weights cancel
        scw[tid] = cosf(a);
        ssw[tid] = sinf(a);
    }
    __syncthreads();

    const int i = blockIdx.x * 256 + tid;

    // ---- load 16 features (64B per lane, dense across wave) ----
    const float4* xin = reinterpret_cast<const float4*>(x + (size_t)i * 16);
    float4 x0 = xin[0], x1 = xin[1], x2 = xin[2], x3 = xin[3];

    // half-angle = mean(x[4q:4q+4]) * pi/2
    const float QPI = 0.25f * 1.57079632679489662f;
    float m0 = (x0.x + x0.y + x0.z + x0.w) * QPI;
    float m1 = (x1.x + x1.y + x1.z + x1.w) * QPI;
    float m2 = (x2.x + x2.y + x2.z + x2.w) * QPI;
    float m3 = (x3.x + x3.y + x3.z + x3.w) * QPI;

    float c0 = __cosf(m0), s0 = __sinf(m0);
    float c1 = __cosf(m1), s1 = __sinf(m1);
    float c2 = __cosf(m2), s2 = __sinf(m2);
    float c3 = __cosf(m3), s3 = __sinf(m3);

    // ---- real product state, qubit q <-> bit (3-q) of flat index ----
    float p[16];
    {
        float q01[4] = { c0 * c1, c0 * s1, s0 * c1, s0 * s1 };
        float q23[4] = { c2 * c3, c2 * s3, s2 * c3, s2 * s3 };
#pragma unroll
        for (int a = 0; a < 4; ++a)
#pragma unroll
            for (int b = 0; b < 4; ++b)
                p[a * 4 + b] = q01[a] * q23[b];
    }

    // ---- CNOT chain: pure compile-time permutations ----
#define SWAPP(A, B) { float _t = p[A]; p[A] = p[B]; p[B] = _t; }
    // CNOT(0,1): control bit3, target bit2
    SWAPP(8, 12) SWAPP(9, 13) SWAPP(10, 14) SWAPP(11, 15)
    // CNOT(1,2): control bit2, target bit1
    SWAPP(4, 6) SWAPP(5, 7) SWAPP(12, 14) SWAPP(13, 15)
    // CNOT(2,3): control bit1, target bit0
    SWAPP(2, 3) SWAPP(6, 7) SWAPP(10, 11) SWAPP(14, 15)
#undef SWAPP

    // ---- trainable RY per qubit (real rotations) ----
    float cw0 = scw[0], sw0 = ssw[0];
    float cw1 = scw[1], sw1 = ssw[1];
    float cw2 = scw[2], sw2 = ssw[2];
    float cw3 = scw[3], sw3 = ssw[3];

    // qubit0: pairs (k, k+8)
#pragma unroll
    for (int k = 0; k < 8; ++k) {
        float a0 = p[k], a1 = p[k + 8];
        p[k]     = cw0 * a0 - sw0 * a1;
        p[k + 8] = sw0 * a0 + cw0 * a1;
    }
    // qubit1: pairs (i0, i0+4), i0 in {0..3, 8..11}
#pragma unroll
    for (int g = 0; g < 2; ++g)
#pragma unroll
        for (int k = 0; k < 4; ++k) {
            int i0 = g * 8 + k;
            float a0 = p[i0], a1 = p[i0 + 4];
            p[i0]     = cw1 * a0 - sw1 * a1;
            p[i0 + 4] = sw1 * a0 + cw1 * a1;
        }
    // qubit2: pairs (i0, i0+2), i0 in {0,1,4,5,8,9,12,13}
#pragma unroll
    for (int g = 0; g < 4; ++g)
#pragma unroll
        for (int k = 0; k < 2; ++k) {
            int i0 = g * 4 + k;
            float a0 = p[i0], a1 = p[i0 + 2];
            p[i0]     = cw2 * a0 - sw2 * a1;
            p[i0 + 2] = sw2 * a0 + cw2 * a1;
        }
    // qubit3: pairs (i0, i0+1), even i0
#pragma unroll
    for (int g = 0; g < 8; ++g) {
        int i0 = g * 2;
        float a0 = p[i0], a1 = p[i0 + 1];
        p[i0]     = cw3 * a0 - sw3 * a1;
        p[i0 + 1] = sw3 * a0 + cw3 * a1;
    }

    // ---- PauliZ expvals: signed sums of probabilities ----
    float z[4] = { 0.f, 0.f, 0.f, 0.f };
#pragma unroll
    for (int ii = 0; ii < 16; ++ii) {
        float pr = p[ii] * p[ii];
        z[0] += (ii & 8) ? -pr : pr;
        z[1] += (ii & 4) ? -pr : pr;
        z[2] += (ii & 2) ? -pr : pr;
        z[3] += (ii & 1) ? -pr : pr;
    }

    // ---- MLP: 4 -> 16 -> 32 -> 16, weights from LDS (broadcast) ----
    float h1[16];
#pragma unroll
    for (int j = 0; j < 16; ++j) {
        float acc = sb1[j];
#pragma unroll
        for (int k = 0; k < 4; ++k) acc += z[k] * sW1[j * 4 + k];
        h1[j] = fmaxf(acc, 0.f);
    }
    float h2[32];
#pragma unroll
    for (int j = 0; j < 32; ++j) {
        float acc = sb2[j];
#pragma unroll
        for (int k = 0; k < 16; ++k) acc += h1[k] * sW2[j * 16 + k];
        h2[j] = fmaxf(acc, 0.f);
    }
    float o[16];
#pragma unroll
    for (int j = 0; j < 16; ++j) {
        float acc = sb3[j];
#pragma unroll
        for (int k = 0; k < 32; ++k) acc += h2[k] * sW3[j * 32 + k];
        o[j] = acc;
    }

    float4* op = reinterpret_cast<float4*>(out + (size_t)i * 16);
    op[0] = make_float4(o[0],  o[1],  o[2],  o[3]);
    op[1] = make_float4(o[4],  o[5],  o[6],  o[7]);
    op[2] = make_float4(o[8],  o[9],  o[10], o[11]);
    op[3] = make_float4(o[12], o[13], o[14], o[15]);
}

extern "C" void kernel_launch(void* const* d_in, const int* in_sizes, int n_in,
                              void* d_out, int out_size, void* d_ws, size_t ws_size,
                              hipStream_t stream) {
    const float* x  = (const float*)d_in[0];
    const float* qw = (const float*)d_in[1];
    const float* W1 = (const float*)d_in[2];
    const float* b1 = (const float*)d_in[3];
    const float* W2 = (const float*)d_in[4];
    const float* b2 = (const float*)d_in[5];
    const float* W3 = (const float*)d_in[6];
    const float* b3 = (const float*)d_in[7];
    float* out = (float*)d_out;

    const int B = in_sizes[0] / 16;           // 1048576
    const int block = 256;
    hqae_kernel<<<B / block, block, 0, stream>>>(x, qw, W1, b1, W2, b2, W3, b3, out);
}